// Round 9
// baseline (101.476 us; speedup 1.0000x reference)
//
#include <hip/hip_runtime.h>
#include <hip/hip_fp16.h>
#include <math.h>

// PerVertQuaternion, round 9: sorted-order face math + light accumulate.
//
// R8 diagnosis: accum_kernel = 57us of 83 (VALUBusy 62%, occ 45%): face math
// executed inside a divergent variable-length run loop (~6x VALU efficiency
// loss). Fix: compute face math in a flat kernel over the SORTED order e
// (S1[e] coalesced read, W4[e] coalesced write -- the scatter already
// happened in the 4B i0 sort), leaving accum as a trivial contiguous
// S1+W read + 4 LDS atomics + coalesced T write.
//
// Session law: scattered global WRITES are catastrophic (~19G sectors/s
// write-through); scattered global READS are cheap (L2/L3 absorb).
//
// Pipeline: zero(E) -> sort (256 blk, histogram+prefix+block-major S1,
// unstructured faces inline -> E atomics) -> facemath (e-order, W4[e]) ->
// accum (per bucket: runs -> LDS f32 -> T) -> finish (T[v]+T[v-1]+T[v-2]+E).

#define BS      256     // bases per bucket
#define NBMAX   2048    // max buckets (V <= 524288)
#define NBLK1   256     // sort blocks
#define CHMAX   4096    // max faces per sort block (F <= 1,048,576)

struct V3 { float x, y, z; };

__device__ __forceinline__ V3 v3sub(const V3& a, const V3& b) {
    return V3{a.x - b.x, a.y - b.y, a.z - b.z};
}
__device__ __forceinline__ V3 v3cross(const V3& a, const V3& b) {
    return V3{a.y * b.z - a.z * b.y,
              a.z * b.x - a.x * b.z,
              a.x * b.y - a.y * b.x};
}
__device__ __forceinline__ float v3dot(const V3& a, const V3& b) {
    return a.x * b.x + a.y * b.y + a.z * b.z;
}
__device__ __forceinline__ V3 v3nrm(const V3& v) {
    float n = sqrtf(v3dot(v, v));
    float inv = 1.0f / fmaxf(n, 1e-12f);
    return V3{v.x * inv, v.y * inv, v.z * inv};
}
__device__ __forceinline__ V3 loadv(const float* __restrict__ p, int i) {
    return V3{p[3 * i], p[3 * i + 1], p[3 * i + 2]};
}

__device__ __forceinline__ void tri2frame(const V3& a, const V3& b, const V3& c,
                                          V3& X, V3& Y, V3& Z) {
    V3 n = v3nrm(v3cross(v3sub(b, a), v3sub(c, a)));
    V3 d = v3sub(b, a);
    X = v3nrm(v3cross(d, n));
    Y = v3nrm(v3cross(d, X));
    Z = v3nrm(d);
}

__device__ __forceinline__ void face_core(V3 ca, V3 cb, V3 cc,
                                          V3 da, V3 db, V3 dc,
                                          float& w0, float& w1, float& w2, float& w3) {
    V3 fn = v3cross(v3sub(cc, cb), v3sub(ca, cb));
    float area = 0.5f * sqrtf(v3dot(fn, fn));

    V3 Xc, Yc, Zc, Xd, Yd, Zd;
    tri2frame(ca, cb, cc, Xc, Yc, Zc);
    tri2frame(da, db, dc, Xd, Yd, Zd);

    // Rot = R_deform * R_cano^T (orthonormal frames -> inv == transpose)
    float Rd[3][3] = {{Xd.x, Yd.x, Zd.x}, {Xd.y, Yd.y, Zd.y}, {Xd.z, Yd.z, Zd.z}};
    float Rc[3][3] = {{Xc.x, Yc.x, Zc.x}, {Xc.y, Yc.y, Zc.y}, {Xc.z, Yc.z, Zc.z}};
    float m00 = Rd[0][0]*Rc[0][0] + Rd[0][1]*Rc[0][1] + Rd[0][2]*Rc[0][2];
    float m01 = Rd[0][0]*Rc[1][0] + Rd[0][1]*Rc[1][1] + Rd[0][2]*Rc[1][2];
    float m02 = Rd[0][0]*Rc[2][0] + Rd[0][1]*Rc[2][1] + Rd[0][2]*Rc[2][2];
    float m10 = Rd[1][0]*Rc[0][0] + Rd[1][1]*Rc[0][1] + Rd[1][2]*Rc[0][2];
    float m11 = Rd[1][0]*Rc[1][0] + Rd[1][1]*Rc[1][1] + Rd[1][2]*Rc[1][2];
    float m12 = Rd[1][0]*Rc[2][0] + Rd[1][1]*Rc[2][1] + Rd[1][2]*Rc[2][2];
    float m20 = Rd[2][0]*Rc[0][0] + Rd[2][1]*Rc[0][1] + Rd[2][2]*Rc[0][2];
    float m21 = Rd[2][0]*Rc[1][0] + Rd[2][1]*Rc[1][1] + Rd[2][2]*Rc[1][2];
    float m22 = Rd[2][0]*Rc[2][0] + Rd[2][1]*Rc[2][1] + Rd[2][2]*Rc[2][2];

    float t0 = 1.0f + m00 + m11 + m22;
    float t1 = 1.0f + m00 - m11 - m22;
    float t2 = 1.0f - m00 + m11 - m22;
    float t3 = 1.0f - m00 - m11 + m22;
    float qa0 = t0 > 0.0f ? sqrtf(t0) : 0.0f;
    float qa1 = t1 > 0.0f ? sqrtf(t1) : 0.0f;
    float qa2 = t2 > 0.0f ? sqrtf(t2) : 0.0f;
    float qa3 = t3 > 0.0f ? sqrtf(t3) : 0.0f;

    int best = 0; float qb = qa0;
    if (qa1 > qb) { best = 1; qb = qa1; }
    if (qa2 > qb) { best = 2; qb = qa2; }
    if (qa3 > qb) { best = 3; qb = qa3; }

    float q0, q1, q2, q3;
    if (best == 0)      { q0 = qa0*qa0; q1 = m21-m12; q2 = m02-m20; q3 = m10-m01; }
    else if (best == 1) { q0 = m21-m12; q1 = qa1*qa1; q2 = m10+m01; q3 = m02+m20; }
    else if (best == 2) { q0 = m02-m20; q1 = m10+m01; q2 = qa2*qa2; q3 = m12+m21; }
    else                { q0 = m10-m01; q1 = m20+m02; q2 = m21+m12; q3 = qa3*qa3; }
    float scale = area / (2.0f * fmaxf(qb, 0.1f));
    w0 = q0 * scale; w1 = q1 * scale; w2 = q2 * scale; w3 = q3 * scale;
}

__device__ __forceinline__ void face_math(const float* __restrict__ mesh,
                                          const float* __restrict__ cano,
                                          int i0, int i1, int i2,
                                          float& w0, float& w1, float& w2, float& w3) {
    face_core(loadv(cano, i0), loadv(cano, i1), loadv(cano, i2),
              loadv(mesh, i0), loadv(mesh, i1), loadv(mesh, i2),
              w0, w1, w2, w3);
}

__device__ __forceinline__ bool is_structured(int i0, int i1, int i2, int V) {
    int e1 = (i0 + 1 < V) ? i0 + 1 : i0 + 1 - V;
    int e2 = (i0 + 2 < V) ? i0 + 2 : i0 + 2 - V;
    return (i1 == e1) & (i2 == e2);
}

// ---------------- P0: zero E ------------------------------------------------
__global__ __launch_bounds__(256)
void zero_kernel(float4* __restrict__ E4, int nE4) {
    int stride = gridDim.x * 256;
    for (int i = blockIdx.x * 256 + threadIdx.x; i < nE4; i += stride)
        E4[i] = make_float4(0.f, 0.f, 0.f, 0.f);
}

// ---------------- P1: per-block counting sort into block-major S1 -----------
__global__ __launch_bounds__(1024)
void sort_kernel(const float* __restrict__ mesh,
                 const float* __restrict__ cano,
                 const int* __restrict__ faces,
                 unsigned int* __restrict__ Hoff,   // [NBLK1][NB] off|cnt<<16
                 int* __restrict__ S1,              // [NBLK1][CHUNKF] block-major
                 int* __restrict__ blkCnt,          // [NBLK1] structured count
                 float* __restrict__ E,
                 int F, int V, int NB, int CHUNKF) {
    __shared__ int h[NBMAX];
    __shared__ int off[NBMAX];
    __shared__ int cnt2[NBMAX];
    __shared__ int S0[CHMAX];
    __shared__ int wsum[16];
    __shared__ int totalS;

    int tid = threadIdx.x;
    for (int b = tid; b < NB; b += 1024) { h[b] = 0; cnt2[b] = 0; }
    __syncthreads();

    int beg = blockIdx.x * CHUNKF;
    int end = min(F, beg + CHUNKF);

    // pass A: histogram + cache i0 in LDS; unstructured -> E atomics inline
    for (int f = beg + tid; f < end; f += 1024) {
        int i0 = faces[3 * f + 0];
        int i1 = faces[3 * f + 1];
        int i2 = faces[3 * f + 2];
        if (is_structured(i0, i1, i2, V)) {
            S0[f - beg] = i0;
            atomicAdd(&h[i0 >> 8], 1);
        } else {
            S0[f - beg] = -1;
            float w0, w1, w2, w3;
            face_math(mesh, cano, i0, i1, i2, w0, w1, w2, w3);
            atomicAdd(&E[4*i0+0], w0); atomicAdd(&E[4*i0+1], w1);
            atomicAdd(&E[4*i0+2], w2); atomicAdd(&E[4*i0+3], w3);
            atomicAdd(&E[4*i1+0], w0); atomicAdd(&E[4*i1+1], w1);
            atomicAdd(&E[4*i1+2], w2); atomicAdd(&E[4*i1+3], w3);
            atomicAdd(&E[4*i2+0], w0); atomicAdd(&E[4*i2+1], w1);
            atomicAdd(&E[4*i2+2], w2); atomicAdd(&E[4*i2+3], w3);
        }
    }
    __syncthreads();

    // exclusive prefix over h[0..NB) -> off[]
    {
        int e0 = (2 * tid < NB)     ? h[2 * tid]     : 0;
        int e1 = (2 * tid + 1 < NB) ? h[2 * tid + 1] : 0;
        int mysum = e0 + e1;
        int lane = tid & 63, wid = tid >> 6;
        int inc = mysum;
        #pragma unroll
        for (int d = 1; d < 64; d <<= 1) {
            int up = __shfl_up(inc, d);
            if (lane >= d) inc += up;
        }
        if (lane == 63) wsum[wid] = inc;
        __syncthreads();
        if (tid == 0) {
            int run = 0;
            #pragma unroll
            for (int i = 0; i < 16; ++i) { int x = wsum[i]; wsum[i] = run; run += x; }
            totalS = run;
        }
        __syncthreads();
        int excl = wsum[wid] + inc - mysum;
        if (2 * tid < NBMAX)     off[2 * tid]     = excl;
        if (2 * tid + 1 < NBMAX) off[2 * tid + 1] = excl + e0;
    }
    __syncthreads();

    // publish packed run descriptors (coalesced) + chunk total
    for (int b = tid; b < NB; b += 1024)
        Hoff[(size_t)blockIdx.x * NB + b] = (unsigned int)off[b] | ((unsigned int)h[b] << 16);
    if (tid == 0) blkCnt[blockIdx.x] = totalS;

    // pass B: write sorted i0 into block-owned chunk (XCD-local scatter)
    int* S1blk = S1 + (size_t)blockIdx.x * CHUNKF;
    for (int j = tid; j < end - beg; j += 1024) {
        int i0 = S0[j];
        if (i0 >= 0) {
            int b = i0 >> 8;
            int p = atomicAdd(&cnt2[b], 1);
            S1blk[off[b] + p] = i0;
        }
    }
}

// ---------------- P2: face math in sorted order, coalesced W4[e] ------------
__global__ __launch_bounds__(256)
void facemath_kernel(const float* __restrict__ mesh,
                     const float* __restrict__ cano,
                     const int* __restrict__ S1,
                     const int* __restrict__ blkCnt,
                     float4* __restrict__ W4,
                     int V, int CHUNKF, int Etot) {
    int e = blockIdx.x * 256 + threadIdx.x;
    if (e >= Etot) return;
    int blk = e / CHUNKF;
    int j   = e - blk * CHUNKF;
    if (j >= blkCnt[blk]) return;           // gap past chunk's packed region
    int i0 = S1[e];
    int i1 = (i0 + 1 < V) ? i0 + 1 : i0 + 1 - V;
    int i2 = (i0 + 2 < V) ? i0 + 2 : i0 + 2 - V;
    float w0, w1, w2, w3;
    face_math(mesh, cano, i0, i1, i2, w0, w1, w2, w3);
    W4[e] = make_float4(w0, w1, w2, w3);
}

// ---------------- P3: per-bucket accumulate (contiguous reads, LDS f32) -----
__global__ __launch_bounds__(256)
void accum_kernel(const unsigned int* __restrict__ Hoff,
                  const int* __restrict__ S1,
                  const float4* __restrict__ W4,
                  float* __restrict__ T, int V, int NB, int CHUNKF) {
    int b = blockIdx.x;
    if (b >= NB) return;
    __shared__ float Tl[BS * 4];
    for (int i = threadIdx.x; i < BS * 4; i += 256) Tl[i] = 0.0f;
    __syncthreads();

    for (int r = threadIdx.x; r < NBLK1; r += 256) {
        unsigned int pc = Hoff[(size_t)r * NB + b];
        int start = (int)(pc & 0xFFFFu);
        int cnt   = (int)(pc >> 16);
        size_t base = (size_t)r * CHUNKF + start;
        for (int j = 0; j < cnt; ++j) {
            int row = S1[base + j] - b * BS;
            float4 w = W4[base + j];
            atomicAdd(&Tl[row * 4 + 0], w.x);
            atomicAdd(&Tl[row * 4 + 1], w.y);
            atomicAdd(&Tl[row * 4 + 2], w.z);
            atomicAdd(&Tl[row * 4 + 3], w.w);
        }
    }
    __syncthreads();
    int rows = min(BS, V - b * BS);
    for (int t = threadIdx.x; t < rows; t += 256) {
        float4 v = make_float4(Tl[t*4+0], Tl[t*4+1], Tl[t*4+2], Tl[t*4+3]);
        reinterpret_cast<float4*>(T)[b * BS + t] = v;
    }
}

// ---------------- P4: shifted sum + normalize -------------------------------
__global__ void finish_kernel(const float* __restrict__ T,
                              const float* __restrict__ E,
                              float* __restrict__ out, int V) {
    int v = blockIdx.x * blockDim.x + threadIdx.x;
    if (v >= V) return;
    int vm1 = (v >= 1) ? v - 1 : v - 1 + V;
    int vm2 = (v >= 2) ? v - 2 : v - 2 + V;
    float4 t0 = reinterpret_cast<const float4*>(T)[v];
    float4 t1 = reinterpret_cast<const float4*>(T)[vm1];
    float4 t2 = reinterpret_cast<const float4*>(T)[vm2];
    float4 e  = reinterpret_cast<const float4*>(E)[v];
    float x = t0.x + t1.x + t2.x + e.x;
    float y = t0.y + t1.y + t2.y + e.y;
    float z = t0.z + t1.z + t2.z + e.z;
    float w = t0.w + t1.w + t2.w + e.w;
    float n = sqrtf(x * x + y * y + z * z + w * w);
    float inv = 1.0f / fmaxf(n, 1e-6f);
    reinterpret_cast<float4*>(out)[v] = make_float4(x * inv, y * inv, z * inv, w * inv);
}

// ================= fallback paths ===========================================
typedef _Float16 hf2 __attribute__((ext_vector_type(2)));

__device__ __forceinline__ void atomic_pk_add_f16(__half* base, float a, float b) {
#if __has_builtin(__builtin_amdgcn_global_atomic_fadd_v2f16)
    hf2 v; v.x = (_Float16)a; v.y = (_Float16)b;
    __builtin_amdgcn_global_atomic_fadd_v2f16(
        (__attribute__((address_space(1))) hf2*)base, v);
#else
    union { _Float16 h[2]; unsigned int u; } pk;
    pk.h[0] = (_Float16)a; pk.h[1] = (_Float16)b;
    asm volatile("global_atomic_pk_add_f16 %0, %1, off"
                 :: "v"(base), "v"(pk.u) : "memory");
#endif
}

__global__ void face_kernel_f16(const float* __restrict__ mesh,
                                const float* __restrict__ cano,
                                const int* __restrict__ faces,
                                __half* __restrict__ T, float* __restrict__ E,
                                int F, int V) {
    int f = blockIdx.x * blockDim.x + threadIdx.x;
    if (f >= F) return;
    int i0 = faces[3*f+0], i1 = faces[3*f+1], i2 = faces[3*f+2];
    float w0, w1, w2, w3;
    face_math(mesh, cano, i0, i1, i2, w0, w1, w2, w3);
    if (is_structured(i0, i1, i2, V)) {
        __half* t = T + 4 * (size_t)i0;
        atomic_pk_add_f16(t,     w0, w1);
        atomic_pk_add_f16(t + 2, w2, w3);
    } else {
        atomicAdd(&E[4*i0+0], w0); atomicAdd(&E[4*i0+1], w1);
        atomicAdd(&E[4*i0+2], w2); atomicAdd(&E[4*i0+3], w3);
        atomicAdd(&E[4*i1+0], w0); atomicAdd(&E[4*i1+1], w1);
        atomicAdd(&E[4*i1+2], w2); atomicAdd(&E[4*i1+3], w3);
        atomicAdd(&E[4*i2+0], w0); atomicAdd(&E[4*i2+1], w1);
        atomicAdd(&E[4*i2+2], w2); atomicAdd(&E[4*i2+3], w3);
    }
}

__global__ void finish_kernel_f16(const __half* __restrict__ T,
                                  const float* __restrict__ E,
                                  float* __restrict__ out, int V) {
    int v = blockIdx.x * blockDim.x + threadIdx.x;
    if (v >= V) return;
    int vm1 = (v >= 1) ? v - 1 : v - 1 + V;
    int vm2 = (v >= 2) ? v - 2 : v - 2 + V;
    const __half2* p0 = reinterpret_cast<const __half2*>(T + 4 * (size_t)v);
    const __half2* p1 = reinterpret_cast<const __half2*>(T + 4 * (size_t)vm1);
    const __half2* p2 = reinterpret_cast<const __half2*>(T + 4 * (size_t)vm2);
    float2 a01 = __half22float2(p0[0]), a23 = __half22float2(p0[1]);
    float2 b01 = __half22float2(p1[0]), b23 = __half22float2(p1[1]);
    float2 c01 = __half22float2(p2[0]), c23 = __half22float2(p2[1]);
    float4 e = reinterpret_cast<const float4*>(E)[v];
    float x = a01.x + b01.x + c01.x + e.x;
    float y = a01.y + b01.y + c01.y + e.y;
    float z = a23.x + b23.x + c23.x + e.z;
    float w = a23.y + b23.y + c23.y + e.w;
    float n = sqrtf(x * x + y * y + z * z + w * w);
    float inv = 1.0f / fmaxf(n, 1e-6f);
    reinterpret_cast<float4*>(out)[v] = make_float4(x * inv, y * inv, z * inv, w * inv);
}

__global__ void face_kernel_direct(const float* __restrict__ mesh,
                                   const float* __restrict__ cano,
                                   const int* __restrict__ faces,
                                   float* __restrict__ out, int F) {
    int f = blockIdx.x * blockDim.x + threadIdx.x;
    if (f >= F) return;
    int i0 = faces[3*f+0], i1 = faces[3*f+1], i2 = faces[3*f+2];
    float w0, w1, w2, w3;
    face_math(mesh, cano, i0, i1, i2, w0, w1, w2, w3);
    atomicAdd(&out[4*i0+0], w0); atomicAdd(&out[4*i0+1], w1);
    atomicAdd(&out[4*i0+2], w2); atomicAdd(&out[4*i0+3], w3);
    atomicAdd(&out[4*i1+0], w0); atomicAdd(&out[4*i1+1], w1);
    atomicAdd(&out[4*i1+2], w2); atomicAdd(&out[4*i1+3], w3);
    atomicAdd(&out[4*i2+0], w0); atomicAdd(&out[4*i2+1], w1);
    atomicAdd(&out[4*i2+2], w2); atomicAdd(&out[4*i2+3], w3);
}

__global__ void norm_kernel(float* __restrict__ out, int V) {
    int v = blockIdx.x * blockDim.x + threadIdx.x;
    if (v >= V) return;
    float4 q = reinterpret_cast<float4*>(out)[v];
    float n = sqrtf(q.x*q.x + q.y*q.y + q.z*q.z + q.w*q.w);
    float inv = 1.0f / fmaxf(n, 1e-6f);
    reinterpret_cast<float4*>(out)[v] = make_float4(q.x*inv, q.y*inv, q.z*inv, q.w*inv);
}

extern "C" void kernel_launch(void* const* d_in, const int* in_sizes, int n_in,
                              void* d_out, int out_size, void* d_ws, size_t ws_size,
                              hipStream_t stream) {
    const float* mesh  = (const float*)d_in[0];
    const float* cano  = (const float*)d_in[1];
    const int*   faces = (const int*)d_in[2];
    float* out = (float*)d_out;

    int V = in_sizes[0] / 3;
    int F = in_sizes[2] / 3;
    const int TB = 256;
    int NB = (V + BS - 1) / BS;
    int CHUNKF = (F + NBLK1 - 1) / NBLK1;
    int Etot = NBLK1 * CHUNKF;

    // ws layout (4-byte units; all region sizes multiples of 4 -> W aligned)
    size_t oHoff = 0;                                   // NBLK1*NBMAX uints
    size_t oBC   = oHoff + (size_t)NBLK1 * NBMAX;       // NBLK1 ints
    size_t oS1   = oBC   + NBLK1;                       // Etot ints
    size_t oW    = oS1   + (size_t)Etot;                // Etot*4 floats
    size_t oT    = oW    + (size_t)Etot * 4;            // V*4 floats
    size_t oE    = oT    + (size_t)V * 4;               // V*4 floats
    size_t needFull = (oE + (size_t)V * 4) * 4;

    size_t bytesTf16 = (size_t)V * 4 * sizeof(__half);
    size_t bytesEf32 = (size_t)V * 4 * sizeof(float);

    if (ws_size >= needFull && NB <= NBMAX && CHUNKF <= CHMAX) {
        unsigned int* Hoff = (unsigned int*)d_ws + oHoff;
        int*    blkCnt = (int*)d_ws + oBC;
        int*    S1     = (int*)d_ws + oS1;
        float4* W4     = (float4*)((float*)d_ws + oW);
        float*  T      = (float*)d_ws + oT;
        float*  E      = (float*)d_ws + oE;

        zero_kernel<<<1024, 256, 0, stream>>>((float4*)E, V);
        sort_kernel<<<NBLK1, 1024, 0, stream>>>(mesh, cano, faces, Hoff, S1, blkCnt,
                                                E, F, V, NB, CHUNKF);
        facemath_kernel<<<(Etot + 255) / 256, 256, 0, stream>>>(mesh, cano, S1, blkCnt,
                                                                W4, V, CHUNKF, Etot);
        accum_kernel<<<NB, 256, 0, stream>>>(Hoff, S1, W4, T, V, NB, CHUNKF);
        finish_kernel<<<(V + TB - 1) / TB, TB, 0, stream>>>(T, E, out, V);
    } else if (ws_size >= bytesTf16 + bytesEf32) {
        __half* T = (__half*)d_ws;
        float*  E = (float*)((char*)d_ws + bytesTf16);
        (void)hipMemsetAsync(d_ws, 0, bytesTf16 + bytesEf32, stream);
        face_kernel_f16<<<(F + TB - 1) / TB, TB, 0, stream>>>(mesh, cano, faces, T, E, F, V);
        finish_kernel_f16<<<(V + TB - 1) / TB, TB, 0, stream>>>(T, E, out, V);
    } else {
        (void)hipMemsetAsync(out, 0, (size_t)V * 4 * sizeof(float), stream);
        face_kernel_direct<<<(F + TB - 1) / TB, TB, 0, stream>>>(mesh, cano, faces, out, F);
        norm_kernel<<<(V + TB - 1) / TB, TB, 0, stream>>>(out, V);
    }
}

// Round 10
// 45.367 us; speedup vs baseline: 2.2368x; 2.2368x over previous
//
#include <hip/hip_runtime.h>
#include <hip/hip_fp16.h>
#include <math.h>

// PerVertQuaternion, round 10: dedup by base vertex (count * w).
//
// Key insight: faces are (i0, i0+1, i0+2) mod V, so faces sharing i0 are
// IDENTICAL -> w depends only on i0. Only count[v] is needed:
//   T[v] = count[v] * w(v),  out[v] = nrm(T[v]+T[v-1]+T[v-2]+E[v])
// and w(v) is computed in a flat per-vertex phase where lane t owns row t:
// vertex reads are contiguous/coalesced, zero scattered gathers, 500k
// face_math evals instead of 1M.
//
// R9 lesson: block-major sorted order has run length ~2 -> e-order gathers
// touch ~32 windows per wave (FETCH 149 MB, 51us). Per-vertex math kills
// that entirely. The divergent run-walk survives only for COUNTING (tiny
// body: 1 read + 1 LDS atomic).
//
// Session laws: scattered global WRITES are catastrophic (~19G sectors/s);
// scattered global READS are cheap; rocclr memset is slow (own zero kernel).
//
// Pipeline: zero(E) -> sort (block-major S1 + run descriptors, unstructured
// faces inline -> E atomics) -> accum (count runs in LDS, then flat
// per-row math, coalesced T write) -> finish.

#define BS      256     // bases per bucket
#define NBMAX   2048    // max buckets (V <= 524288)
#define NBLK1   256     // sort blocks
#define CHMAX   4096    // max faces per sort block (F <= 1,048,576)

struct V3 { float x, y, z; };

__device__ __forceinline__ V3 v3sub(const V3& a, const V3& b) {
    return V3{a.x - b.x, a.y - b.y, a.z - b.z};
}
__device__ __forceinline__ V3 v3cross(const V3& a, const V3& b) {
    return V3{a.y * b.z - a.z * b.y,
              a.z * b.x - a.x * b.z,
              a.x * b.y - a.y * b.x};
}
__device__ __forceinline__ float v3dot(const V3& a, const V3& b) {
    return a.x * b.x + a.y * b.y + a.z * b.z;
}
__device__ __forceinline__ V3 v3nrm(const V3& v) {
    float n = sqrtf(v3dot(v, v));
    float inv = 1.0f / fmaxf(n, 1e-12f);
    return V3{v.x * inv, v.y * inv, v.z * inv};
}
__device__ __forceinline__ V3 loadv(const float* __restrict__ p, int i) {
    return V3{p[3 * i], p[3 * i + 1], p[3 * i + 2]};
}

__device__ __forceinline__ void tri2frame(const V3& a, const V3& b, const V3& c,
                                          V3& X, V3& Y, V3& Z) {
    V3 n = v3nrm(v3cross(v3sub(b, a), v3sub(c, a)));
    V3 d = v3sub(b, a);
    X = v3nrm(v3cross(d, n));
    Y = v3nrm(v3cross(d, X));
    Z = v3nrm(d);
}

__device__ __forceinline__ void face_core(V3 ca, V3 cb, V3 cc,
                                          V3 da, V3 db, V3 dc,
                                          float& w0, float& w1, float& w2, float& w3) {
    V3 fn = v3cross(v3sub(cc, cb), v3sub(ca, cb));
    float area = 0.5f * sqrtf(v3dot(fn, fn));

    V3 Xc, Yc, Zc, Xd, Yd, Zd;
    tri2frame(ca, cb, cc, Xc, Yc, Zc);
    tri2frame(da, db, dc, Xd, Yd, Zd);

    // Rot = R_deform * R_cano^T (orthonormal frames -> inv == transpose)
    float Rd[3][3] = {{Xd.x, Yd.x, Zd.x}, {Xd.y, Yd.y, Zd.y}, {Xd.z, Yd.z, Zd.z}};
    float Rc[3][3] = {{Xc.x, Yc.x, Zc.x}, {Xc.y, Yc.y, Zc.y}, {Xc.z, Yc.z, Zc.z}};
    float m00 = Rd[0][0]*Rc[0][0] + Rd[0][1]*Rc[0][1] + Rd[0][2]*Rc[0][2];
    float m01 = Rd[0][0]*Rc[1][0] + Rd[0][1]*Rc[1][1] + Rd[0][2]*Rc[1][2];
    float m02 = Rd[0][0]*Rc[2][0] + Rd[0][1]*Rc[2][1] + Rd[0][2]*Rc[2][2];
    float m10 = Rd[1][0]*Rc[0][0] + Rd[1][1]*Rc[0][1] + Rd[1][2]*Rc[0][2];
    float m11 = Rd[1][0]*Rc[1][0] + Rd[1][1]*Rc[1][1] + Rd[1][2]*Rc[1][2];
    float m12 = Rd[1][0]*Rc[2][0] + Rd[1][1]*Rc[2][1] + Rd[1][2]*Rc[2][2];
    float m20 = Rd[2][0]*Rc[0][0] + Rd[2][1]*Rc[0][1] + Rd[2][2]*Rc[0][2];
    float m21 = Rd[2][0]*Rc[1][0] + Rd[2][1]*Rc[1][1] + Rd[2][2]*Rc[1][2];
    float m22 = Rd[2][0]*Rc[2][0] + Rd[2][1]*Rc[2][1] + Rd[2][2]*Rc[2][2];

    float t0 = 1.0f + m00 + m11 + m22;
    float t1 = 1.0f + m00 - m11 - m22;
    float t2 = 1.0f - m00 + m11 - m22;
    float t3 = 1.0f - m00 - m11 + m22;
    float qa0 = t0 > 0.0f ? sqrtf(t0) : 0.0f;
    float qa1 = t1 > 0.0f ? sqrtf(t1) : 0.0f;
    float qa2 = t2 > 0.0f ? sqrtf(t2) : 0.0f;
    float qa3 = t3 > 0.0f ? sqrtf(t3) : 0.0f;

    int best = 0; float qb = qa0;
    if (qa1 > qb) { best = 1; qb = qa1; }
    if (qa2 > qb) { best = 2; qb = qa2; }
    if (qa3 > qb) { best = 3; qb = qa3; }

    float q0, q1, q2, q3;
    if (best == 0)      { q0 = qa0*qa0; q1 = m21-m12; q2 = m02-m20; q3 = m10-m01; }
    else if (best == 1) { q0 = m21-m12; q1 = qa1*qa1; q2 = m10+m01; q3 = m02+m20; }
    else if (best == 2) { q0 = m02-m20; q1 = m10+m01; q2 = qa2*qa2; q3 = m12+m21; }
    else                { q0 = m10-m01; q1 = m20+m02; q2 = m21+m12; q3 = qa3*qa3; }
    float scale = area / (2.0f * fmaxf(qb, 0.1f));
    w0 = q0 * scale; w1 = q1 * scale; w2 = q2 * scale; w3 = q3 * scale;
}

__device__ __forceinline__ void face_math(const float* __restrict__ mesh,
                                          const float* __restrict__ cano,
                                          int i0, int i1, int i2,
                                          float& w0, float& w1, float& w2, float& w3) {
    face_core(loadv(cano, i0), loadv(cano, i1), loadv(cano, i2),
              loadv(mesh, i0), loadv(mesh, i1), loadv(mesh, i2),
              w0, w1, w2, w3);
}

__device__ __forceinline__ bool is_structured(int i0, int i1, int i2, int V) {
    int e1 = (i0 + 1 < V) ? i0 + 1 : i0 + 1 - V;
    int e2 = (i0 + 2 < V) ? i0 + 2 : i0 + 2 - V;
    return (i1 == e1) & (i2 == e2);
}

// ---------------- P0: zero E ------------------------------------------------
__global__ __launch_bounds__(256)
void zero_kernel(float4* __restrict__ E4, int nE4) {
    int stride = gridDim.x * 256;
    for (int i = blockIdx.x * 256 + threadIdx.x; i < nE4; i += stride)
        E4[i] = make_float4(0.f, 0.f, 0.f, 0.f);
}

// ---------------- P1: per-block counting sort into block-major S1 -----------
__global__ __launch_bounds__(1024)
void sort_kernel(const float* __restrict__ mesh,
                 const float* __restrict__ cano,
                 const int* __restrict__ faces,
                 unsigned int* __restrict__ Hoff,   // [NBLK1][NB] off|cnt<<16
                 int* __restrict__ S1,              // [NBLK1][CHUNKF] block-major
                 float* __restrict__ E,
                 int F, int V, int NB, int CHUNKF) {
    __shared__ int h[NBMAX];
    __shared__ int off[NBMAX];
    __shared__ int cnt2[NBMAX];
    __shared__ int S0[CHMAX];
    __shared__ int wsum[16];

    int tid = threadIdx.x;
    for (int b = tid; b < NB; b += 1024) { h[b] = 0; cnt2[b] = 0; }
    __syncthreads();

    int beg = blockIdx.x * CHUNKF;
    int end = min(F, beg + CHUNKF);

    // pass A: histogram + cache i0 in LDS; unstructured -> E atomics inline
    for (int f = beg + tid; f < end; f += 1024) {
        int i0 = faces[3 * f + 0];
        int i1 = faces[3 * f + 1];
        int i2 = faces[3 * f + 2];
        if (is_structured(i0, i1, i2, V)) {
            S0[f - beg] = i0;
            atomicAdd(&h[i0 >> 8], 1);
        } else {
            S0[f - beg] = -1;
            float w0, w1, w2, w3;
            face_math(mesh, cano, i0, i1, i2, w0, w1, w2, w3);
            atomicAdd(&E[4*i0+0], w0); atomicAdd(&E[4*i0+1], w1);
            atomicAdd(&E[4*i0+2], w2); atomicAdd(&E[4*i0+3], w3);
            atomicAdd(&E[4*i1+0], w0); atomicAdd(&E[4*i1+1], w1);
            atomicAdd(&E[4*i1+2], w2); atomicAdd(&E[4*i1+3], w3);
            atomicAdd(&E[4*i2+0], w0); atomicAdd(&E[4*i2+1], w1);
            atomicAdd(&E[4*i2+2], w2); atomicAdd(&E[4*i2+3], w3);
        }
    }
    __syncthreads();

    // exclusive prefix over h[0..NB) -> off[]
    {
        int e0 = (2 * tid < NB)     ? h[2 * tid]     : 0;
        int e1 = (2 * tid + 1 < NB) ? h[2 * tid + 1] : 0;
        int mysum = e0 + e1;
        int lane = tid & 63, wid = tid >> 6;
        int inc = mysum;
        #pragma unroll
        for (int d = 1; d < 64; d <<= 1) {
            int up = __shfl_up(inc, d);
            if (lane >= d) inc += up;
        }
        if (lane == 63) wsum[wid] = inc;
        __syncthreads();
        if (tid == 0) {
            int run = 0;
            #pragma unroll
            for (int i = 0; i < 16; ++i) { int x = wsum[i]; wsum[i] = run; run += x; }
        }
        __syncthreads();
        int excl = wsum[wid] + inc - mysum;
        if (2 * tid < NBMAX)     off[2 * tid]     = excl;
        if (2 * tid + 1 < NBMAX) off[2 * tid + 1] = excl + e0;
    }
    __syncthreads();

    // publish packed run descriptors (coalesced)
    for (int b = tid; b < NB; b += 1024)
        Hoff[(size_t)blockIdx.x * NB + b] = (unsigned int)off[b] | ((unsigned int)h[b] << 16);

    // pass B: write sorted i0 into block-owned chunk (XCD-local scatter)
    int* S1blk = S1 + (size_t)blockIdx.x * CHUNKF;
    for (int j = tid; j < end - beg; j += 1024) {
        int i0 = S0[j];
        if (i0 >= 0) {
            int b = i0 >> 8;
            int p = atomicAdd(&cnt2[b], 1);
            S1blk[off[b] + p] = i0;
        }
    }
}

// ---------------- P2: count runs in LDS, then flat per-row math -------------
__global__ __launch_bounds__(256)
void accum_kernel(const float* __restrict__ mesh,
                  const float* __restrict__ cano,
                  const unsigned int* __restrict__ Hoff,
                  const int* __restrict__ S1,
                  float* __restrict__ T, int V, int NB, int CHUNKF) {
    int b = blockIdx.x;
    if (b >= NB) return;
    __shared__ unsigned int cnt_l[BS];
    cnt_l[threadIdx.x] = 0;
    __syncthreads();

    // phase 1: count residues across this bucket's 256 runs (tiny body)
    {
        int r = threadIdx.x;   // one run per thread (NBLK1 == 256)
        unsigned int pc = Hoff[(size_t)r * NB + b];
        int start = (int)(pc & 0xFFFFu);
        int cnt   = (int)(pc >> 16);
        const int* run = S1 + (size_t)r * CHUNKF + start;
        for (int j = 0; j < cnt; ++j)
            atomicAdd(&cnt_l[run[j] - b * BS], 1u);
    }
    __syncthreads();

    // phase 2: one lane per row; contiguous coalesced vertex reads
    int rows = min(BS, V - b * BS);
    int t = threadIdx.x;
    if (t < rows) {
        int v = b * BS + t;
        unsigned int c = cnt_l[t];
        float4 res = make_float4(0.f, 0.f, 0.f, 0.f);
        if (c > 0) {
            int i1 = (v + 1 < V) ? v + 1 : v + 1 - V;
            int i2 = (v + 2 < V) ? v + 2 : v + 2 - V;
            float w0, w1, w2, w3;
            face_math(mesh, cano, v, i1, i2, w0, w1, w2, w3);
            float fc = (float)c;
            res = make_float4(w0 * fc, w1 * fc, w2 * fc, w3 * fc);
        }
        reinterpret_cast<float4*>(T)[v] = res;
    }
}

// ---------------- P3: shifted sum + normalize -------------------------------
__global__ void finish_kernel(const float* __restrict__ T,
                              const float* __restrict__ E,
                              float* __restrict__ out, int V) {
    int v = blockIdx.x * blockDim.x + threadIdx.x;
    if (v >= V) return;
    int vm1 = (v >= 1) ? v - 1 : v - 1 + V;
    int vm2 = (v >= 2) ? v - 2 : v - 2 + V;
    float4 t0 = reinterpret_cast<const float4*>(T)[v];
    float4 t1 = reinterpret_cast<const float4*>(T)[vm1];
    float4 t2 = reinterpret_cast<const float4*>(T)[vm2];
    float4 e  = reinterpret_cast<const float4*>(E)[v];
    float x = t0.x + t1.x + t2.x + e.x;
    float y = t0.y + t1.y + t2.y + e.y;
    float z = t0.z + t1.z + t2.z + e.z;
    float w = t0.w + t1.w + t2.w + e.w;
    float n = sqrtf(x * x + y * y + z * z + w * w);
    float inv = 1.0f / fmaxf(n, 1e-6f);
    reinterpret_cast<float4*>(out)[v] = make_float4(x * inv, y * inv, z * inv, w * inv);
}

// ================= fallback paths ===========================================
typedef _Float16 hf2 __attribute__((ext_vector_type(2)));

__device__ __forceinline__ void atomic_pk_add_f16(__half* base, float a, float b) {
#if __has_builtin(__builtin_amdgcn_global_atomic_fadd_v2f16)
    hf2 v; v.x = (_Float16)a; v.y = (_Float16)b;
    __builtin_amdgcn_global_atomic_fadd_v2f16(
        (__attribute__((address_space(1))) hf2*)base, v);
#else
    union { _Float16 h[2]; unsigned int u; } pk;
    pk.h[0] = (_Float16)a; pk.h[1] = (_Float16)b;
    asm volatile("global_atomic_pk_add_f16 %0, %1, off"
                 :: "v"(base), "v"(pk.u) : "memory");
#endif
}

__global__ void face_kernel_f16(const float* __restrict__ mesh,
                                const float* __restrict__ cano,
                                const int* __restrict__ faces,
                                __half* __restrict__ T, float* __restrict__ E,
                                int F, int V) {
    int f = blockIdx.x * blockDim.x + threadIdx.x;
    if (f >= F) return;
    int i0 = faces[3*f+0], i1 = faces[3*f+1], i2 = faces[3*f+2];
    float w0, w1, w2, w3;
    face_math(mesh, cano, i0, i1, i2, w0, w1, w2, w3);
    if (is_structured(i0, i1, i2, V)) {
        __half* t = T + 4 * (size_t)i0;
        atomic_pk_add_f16(t,     w0, w1);
        atomic_pk_add_f16(t + 2, w2, w3);
    } else {
        atomicAdd(&E[4*i0+0], w0); atomicAdd(&E[4*i0+1], w1);
        atomicAdd(&E[4*i0+2], w2); atomicAdd(&E[4*i0+3], w3);
        atomicAdd(&E[4*i1+0], w0); atomicAdd(&E[4*i1+1], w1);
        atomicAdd(&E[4*i1+2], w2); atomicAdd(&E[4*i1+3], w3);
        atomicAdd(&E[4*i2+0], w0); atomicAdd(&E[4*i2+1], w1);
        atomicAdd(&E[4*i2+2], w2); atomicAdd(&E[4*i2+3], w3);
    }
}

__global__ void finish_kernel_f16(const __half* __restrict__ T,
                                  const float* __restrict__ E,
                                  float* __restrict__ out, int V) {
    int v = blockIdx.x * blockDim.x + threadIdx.x;
    if (v >= V) return;
    int vm1 = (v >= 1) ? v - 1 : v - 1 + V;
    int vm2 = (v >= 2) ? v - 2 : v - 2 + V;
    const __half2* p0 = reinterpret_cast<const __half2*>(T + 4 * (size_t)v);
    const __half2* p1 = reinterpret_cast<const __half2*>(T + 4 * (size_t)vm1);
    const __half2* p2 = reinterpret_cast<const __half2*>(T + 4 * (size_t)vm2);
    float2 a01 = __half22float2(p0[0]), a23 = __half22float2(p0[1]);
    float2 b01 = __half22float2(p1[0]), b23 = __half22float2(p1[1]);
    float2 c01 = __half22float2(p2[0]), c23 = __half22float2(p2[1]);
    float4 e = reinterpret_cast<const float4*>(E)[v];
    float x = a01.x + b01.x + c01.x + e.x;
    float y = a01.y + b01.y + c01.y + e.y;
    float z = a23.x + b23.x + c23.x + e.z;
    float w = a23.y + b23.y + c23.y + e.w;
    float n = sqrtf(x * x + y * y + z * z + w * w);
    float inv = 1.0f / fmaxf(n, 1e-6f);
    reinterpret_cast<float4*>(out)[v] = make_float4(x * inv, y * inv, z * inv, w * inv);
}

__global__ void face_kernel_direct(const float* __restrict__ mesh,
                                   const float* __restrict__ cano,
                                   const int* __restrict__ faces,
                                   float* __restrict__ out, int F) {
    int f = blockIdx.x * blockDim.x + threadIdx.x;
    if (f >= F) return;
    int i0 = faces[3*f+0], i1 = faces[3*f+1], i2 = faces[3*f+2];
    float w0, w1, w2, w3;
    face_math(mesh, cano, i0, i1, i2, w0, w1, w2, w3);
    atomicAdd(&out[4*i0+0], w0); atomicAdd(&out[4*i0+1], w1);
    atomicAdd(&out[4*i0+2], w2); atomicAdd(&out[4*i0+3], w3);
    atomicAdd(&out[4*i1+0], w0); atomicAdd(&out[4*i1+1], w1);
    atomicAdd(&out[4*i1+2], w2); atomicAdd(&out[4*i1+3], w3);
    atomicAdd(&out[4*i2+0], w0); atomicAdd(&out[4*i2+1], w1);
    atomicAdd(&out[4*i2+2], w2); atomicAdd(&out[4*i2+3], w3);
}

__global__ void norm_kernel(float* __restrict__ out, int V) {
    int v = blockIdx.x * blockDim.x + threadIdx.x;
    if (v >= V) return;
    float4 q = reinterpret_cast<float4*>(out)[v];
    float n = sqrtf(q.x*q.x + q.y*q.y + q.z*q.z + q.w*q.w);
    float inv = 1.0f / fmaxf(n, 1e-6f);
    reinterpret_cast<float4*>(out)[v] = make_float4(q.x*inv, q.y*inv, q.z*inv, q.w*inv);
}

extern "C" void kernel_launch(void* const* d_in, const int* in_sizes, int n_in,
                              void* d_out, int out_size, void* d_ws, size_t ws_size,
                              hipStream_t stream) {
    const float* mesh  = (const float*)d_in[0];
    const float* cano  = (const float*)d_in[1];
    const int*   faces = (const int*)d_in[2];
    float* out = (float*)d_out;

    int V = in_sizes[0] / 3;
    int F = in_sizes[2] / 3;
    const int TB = 256;
    int NB = (V + BS - 1) / BS;
    int CHUNKF = (F + NBLK1 - 1) / NBLK1;

    // ws layout (4-byte units)
    size_t oHoff = 0;                                   // NBLK1*NBMAX uints
    size_t oS1   = oHoff + (size_t)NBLK1 * NBMAX;       // NBLK1*CHUNKF ints
    size_t oT    = oS1   + (size_t)NBLK1 * CHUNKF;      // V*4 floats
    size_t oE    = oT    + (size_t)V * 4;               // V*4 floats
    size_t needFull = (oE + (size_t)V * 4) * 4;

    size_t bytesTf16 = (size_t)V * 4 * sizeof(__half);
    size_t bytesEf32 = (size_t)V * 4 * sizeof(float);

    if (ws_size >= needFull && NB <= NBMAX && CHUNKF <= CHMAX) {
        unsigned int* Hoff = (unsigned int*)d_ws + oHoff;
        int*   S1 = (int*)d_ws + oS1;
        float* T  = (float*)d_ws + oT;
        float* E  = (float*)d_ws + oE;

        zero_kernel<<<1024, 256, 0, stream>>>((float4*)E, V);
        sort_kernel<<<NBLK1, 1024, 0, stream>>>(mesh, cano, faces, Hoff, S1,
                                                E, F, V, NB, CHUNKF);
        accum_kernel<<<NB, 256, 0, stream>>>(mesh, cano, Hoff, S1, T, V, NB, CHUNKF);
        finish_kernel<<<(V + TB - 1) / TB, TB, 0, stream>>>(T, E, out, V);
    } else if (ws_size >= bytesTf16 + bytesEf32) {
        __half* T = (__half*)d_ws;
        float*  E = (float*)((char*)d_ws + bytesTf16);
        (void)hipMemsetAsync(d_ws, 0, bytesTf16 + bytesEf32, stream);
        face_kernel_f16<<<(F + TB - 1) / TB, TB, 0, stream>>>(mesh, cano, faces, T, E, F, V);
        finish_kernel_f16<<<(V + TB - 1) / TB, TB, 0, stream>>>(T, E, out, V);
    } else {
        (void)hipMemsetAsync(out, 0, (size_t)V * 4 * sizeof(float), stream);
        face_kernel_direct<<<(F + TB - 1) / TB, TB, 0, stream>>>(mesh, cano, faces, out, F);
        norm_kernel<<<(V + TB - 1) / TB, TB, 0, stream>>>(out, V);
    }
}